// Round 9
// baseline (305.393 us; speedup 1.0000x reference)
//
#include <hip/hip_runtime.h>
#include <hip/hip_bf16.h>
#include <cstdint>
#include <cstddef>

#define NH   16
#define HD   64
#define CD   1024
#define HARM 32
#define BSZ  2
#define LSEQ 2048
#define NROW (BSZ*LSEQ)   // 4096

typedef __attribute__((ext_vector_type(8))) short short8;     // 8 bf16 (A/B frag)
typedef __attribute__((ext_vector_type(16))) float float16v;  // 32x32 C frag

__device__ inline ushort bf16u(float f) {
    __hip_bfloat16 h = __float2bfloat16(f);
    return *(ushort*)&h;
}
__device__ inline float ubf(ushort u) {
    return __uint_as_float((unsigned)u << 16);
}
__device__ inline unsigned pk2(float a, float b) {
    return (unsigned)bf16u(a) | ((unsigned)bf16u(b) << 16);
}
// C-frag register r -> row offset within 32-row tile
__device__ inline int crow(int r, int half) { return (r & 3) + 8 * (r >> 2) + 4 * half; }

union S8U { short8 v; uint2 u[2]; };

// Half-swap transform (verified flash3..8): C-frag regs (8 packed uints,
// pk[j] = m-values {8*(j>>1)+4h+2*(j&1), +1}) -> one A/B-frag 16-k chunk cc.
// Result frag: lane = former C column, k = former C rows.
__device__ inline short8 cfrag_chunk(const unsigned* pk, int cc, int h) {
    int gb2 = cc * 4;
    unsigned B0, B1, B2, B3;
    {
        unsigned v0 = pk[gb2], v1 = pk[gb2 + 2];
        unsigned send = h ? v0 : v1;
        unsigned rem = (unsigned)__shfl_xor((int)send, 32, 64);
        B0 = h ? rem : v0;
        B2 = h ? v1 : rem;
    }
    {
        unsigned v0 = pk[gb2 + 1], v1 = pk[gb2 + 3];
        unsigned send = h ? v0 : v1;
        unsigned rem = (unsigned)__shfl_xor((int)send, 32, 64);
        B1 = h ? rem : v0;
        B3 = h ? v1 : rem;
    }
    S8U bf;
    bf.u[0] = make_uint2(B0, B1);
    bf.u[1] = make_uint2(B2, B3);
    return bf.v;
}

// ---------------------------------------------------------------------------
// prep: fragment-tile all weights (unchanged, verified).
// ---------------------------------------------------------------------------
__global__ void prep_kern(const float* __restrict__ bq, const float* __restrict__ bk,
                          const float* __restrict__ bv, const float* __restrict__ bo,
                          const float* __restrict__ pq, const float* __restrict__ aq,
                          const float* __restrict__ pk, const float* __restrict__ ak,
                          const float* __restrict__ pv, const float* __restrict__ av,
                          const float* __restrict__ po, const float* __restrict__ ao,
                          ushort* __restrict__ bF, ushort* __restrict__ wqkvF,
                          ushort* __restrict__ wobF) {
    const float QSCALE = 0.125f * 1.44269504088896340736f;  // hd^-0.5 * log2e
    unsigned tid = blockIdx.x * 256 + threadIdx.x;
    if (tid < 16384) {                 // bF
        unsigned l31 = tid & 31, h = (tid >> 5) & 1, kc = (tid >> 6) & 63, proj = tid >> 12;
        const float* bp = (proj == 0) ? bq : (proj == 1) ? bk : (proj == 2) ? bv : bo;
        const float* s = bp + (size_t)l31 * CD + kc * 16 + h * 8;
        float4 f0 = *(const float4*)s, f1 = *(const float4*)(s + 4);
        S8U o;
        o.u[0] = make_uint2(pk2(f0.x, f0.y), pk2(f0.z, f0.w));
        o.u[1] = make_uint2(pk2(f1.x, f1.y), pk2(f1.z, f1.w));
        *(short8*)(bF + (size_t)tid * 8) = o.v;
        return;
    }
    if (tid < 28672) {                 // wqkvF
        unsigned i = tid - 16384;
        unsigned l31 = i & 31, h = (i >> 5) & 1, kc2 = (i >> 6) & 1;
        unsigned ntp = (i >> 7) & 31, proj = i >> 12;
        const float* ph = (proj == 0) ? pq : (proj == 1) ? pk : pv;
        const float* am = (proj == 0) ? aq : (proj == 1) ? ak : av;
        float sc = (proj == 0) ? QSCALE : 1.0f;
        size_t s = (size_t)(ntp * 32 + l31) * HARM + kc2 * 16 + h * 8;
        float4 p0 = *(const float4*)(ph + s), p1 = *(const float4*)(ph + s + 4);
        float4 a0 = *(const float4*)(am + s), a1 = *(const float4*)(am + s + 4);
        S8U o;
        o.u[0] = make_uint2(pk2(a0.x * cosf(p0.x) * sc, a0.y * cosf(p0.y) * sc),
                            pk2(a0.z * cosf(p0.z) * sc, a0.w * cosf(p0.w) * sc));
        o.u[1] = make_uint2(pk2(a1.x * cosf(p1.x) * sc, a1.y * cosf(p1.y) * sc),
                            pk2(a1.z * cosf(p1.z) * sc, a1.w * cosf(p1.w) * sc));
        *(short8*)(wqkvF + (size_t)i * 8) = o.v;
        return;
    }
    {                                  // wobF
        unsigned i = tid - 28672;      // 4096
        unsigned l31 = i & 31, h = (i >> 5) & 1, kc2 = (i >> 6) & 1, nt = i >> 7;
        size_t s = (size_t)(nt * 32 + l31) * HARM + kc2 * 16 + h * 8;
        float4 p0 = *(const float4*)(po + s), p1 = *(const float4*)(po + s + 4);
        float4 a0 = *(const float4*)(ao + s), a1 = *(const float4*)(ao + s + 4);
        S8U o;
        o.u[0] = make_uint2(pk2(a0.x * cosf(p0.x), a0.y * cosf(p0.y)),
                            pk2(a0.z * cosf(p0.z), a0.w * cosf(p0.w)));
        o.u[1] = make_uint2(pk2(a1.x * cosf(p1.x), a1.y * cosf(p1.y)),
                            pk2(a1.z * cosf(p1.z), a1.w * cosf(p1.w)));
        *(short8*)(wobF + (size_t)i * 8) = o.v;
    }
}

// ---------------------------------------------------------------------------
// res_part: unchanged (verified round 8).
//   respart[kseg][rg][p][r][lane]  fp32, 6 MB total
// ---------------------------------------------------------------------------
__global__ __launch_bounds__(256) void res_part_kern(const float* __restrict__ x,
                                                     const ushort* __restrict__ bF,
                                                     float* __restrict__ respart) {
    __shared__ ushort xs[32 * 256];          // 16 KB
    __shared__ float red[4 * 16 * 64];       // 16 KB
    const int t = threadIdx.x, wave = t >> 6, lane = t & 63;
    const int l31 = lane & 31, h = lane >> 5;
    const int kseg = blockIdx.x & 3, rg = blockIdx.x >> 2;
    const int n0 = rg * 32;

#pragma unroll
    for (int i = 0; i < 8; i++) {
        int idx = i * 256 + t, row = idx >> 6, c4 = idx & 63;
        float4 v = *(const float4*)(x + (size_t)(n0 + row) * CD + kseg * 256 + c4 * 4);
        int chunk = (c4 >> 1) ^ (row & 15), sub = c4 & 1;
        *(ushort4*)(&xs[row * 256 + chunk * 8 + sub * 4]) =
            make_ushort4(bf16u(v.x), bf16u(v.y), bf16u(v.z), bf16u(v.w));
    }
    __syncthreads();

    float16v resC[3] = {};
#pragma unroll
    for (int kci = 0; kci < 4; kci++) {
        int c = wave * 8 + kci * 2 + h;
        short8 bx = *(const short8*)(&xs[l31 * 256 + (c ^ (l31 & 15)) * 8]);
        int kcg = kseg * 16 + wave * 4 + kci;
#pragma unroll
        for (int p = 0; p < 3; p++) {
            short8 a = *(const short8*)(bF + ((size_t)((p * 64 + kcg) * 2 + h) * 32 + l31) * 8);
            resC[p] = __builtin_amdgcn_mfma_f32_32x32x16_bf16(a, bx, resC[p], 0, 0, 0);
        }
    }
    float* outb = respart + ((size_t)(kseg * 128 + rg) * 3) * 1024;
    for (int p = 0; p < 3; p++) {
        __syncthreads();
#pragma unroll
        for (int r = 0; r < 16; r++) red[wave * 1024 + r * 64 + lane] = resC[p][r];
        __syncthreads();
#pragma unroll
        for (int i = 0; i < 4; i++) {
            int e = i * 256 + t;
            outb[p * 1024 + e] = (red[e] + red[1024 + e]) + (red[2048 + e] + red[3072 + e]);
        }
    }
}

// ---------------------------------------------------------------------------
// qkv: unchanged (verified round 8).
// ---------------------------------------------------------------------------
__global__ __launch_bounds__(256) void qkv_kern(const float* __restrict__ respart,
                                                const ushort* __restrict__ wqkvF,
                                                ushort* __restrict__ qtile,
                                                ushort* __restrict__ ktile,
                                                ushort* __restrict__ vtile) {
    const int t = threadIdx.x, wave = t >> 6, lane = t & 63;
    const int l31 = lane & 31, h = lane >> 5;
    const int seg = blockIdx.x & 3, rest = blockIdx.x >> 2;
    const int b = rest >> 6, l0q = rest & 63;

    short8 rf[3][2];
#pragma unroll
    for (int p = 0; p < 3; p++) {
        float cf[16];
#pragma unroll
        for (int r = 0; r < 16; r++) {
            const float* pp = respart + (size_t)p * 1024 + r * 64 + lane;
            cf[r] = (pp[(size_t)rest * 3072] +
                     pp[(size_t)(128 + rest) * 3072]) +
                    (pp[(size_t)(256 + rest) * 3072] +
                     pp[(size_t)(384 + rest) * 3072]);
        }
        unsigned pkr[8];
#pragma unroll
        for (int j = 0; j < 8; j++) pkr[j] = pk2(cf[2 * j], cf[2 * j + 1]);
        rf[p][0] = cfrag_chunk(pkr, 0, h);
        rf[p][1] = cfrag_chunk(pkr, 1, h);
    }

    const int kblk = l0q >> 1, mtk = l0q & 1;
    for (int i = 0; i < 6; i++) {
        int nt = (seg * 4 + wave) * 6 + i;
        int proj = nt >> 5, ntp = nt & 31;
        int head = ntp >> 1, sub = ntp & 1;
        const ushort* wp = wqkvF + ((size_t)(proj * 32 + ntp) * 4) * 256;  // [kc2][h][l31][8]
        short8 wf0 = *(const short8*)(wp + (size_t)h * 256 + l31 * 8);
        short8 wf1 = *(const short8*)(wp + (size_t)(2 + h) * 256 + l31 * 8);
        float16v c = {};
        if (proj < 2) {   // A=w (lane=ch), B=res (lane=row) -> C col=row
            c = __builtin_amdgcn_mfma_f32_32x32x16_bf16(wf0, rf[proj][0], c, 0, 0, 0);
            c = __builtin_amdgcn_mfma_f32_32x32x16_bf16(wf1, rf[proj][1], c, 0, 0, 0);
        } else {          // A=res (lane=row), B=w (lane=ch) -> C col=ch
            c = __builtin_amdgcn_mfma_f32_32x32x16_bf16(rf[2][0], wf0, c, 0, 0, 0);
            c = __builtin_amdgcn_mfma_f32_32x32x16_bf16(rf[2][1], wf1, c, 0, 0, 0);
        }
        unsigned pkc[8];
#pragma unroll
        for (int j = 0; j < 8; j++) pkc[j] = pk2(c[2 * j], c[2 * j + 1]);

        if (proj == 0) {
            ushort* base = qtile + (((size_t)(b * NH + head) * 64 + l0q)) * 2048;
#pragma unroll
            for (int cc = 0; cc < 2; cc++)
                *(short8*)(base + (sub * 2 + cc) * 512 + h * 256 + l31 * 8) =
                    cfrag_chunk(pkc, cc, h);
        } else if (proj == 1) {
            ushort* base = ktile + ((size_t)(b * NH + head) * 32 + kblk) * 4096 + mtk * 2048;
#pragma unroll
            for (int cc = 0; cc < 2; cc++)
                *(short8*)(base + (sub * 2 + cc) * 512 + h * 256 + l31 * 8) =
                    cfrag_chunk(pkc, cc, h);
        } else {
            ushort* base = vtile + ((size_t)(b * NH + head) * 32 + kblk) * 4096 + sub * 2048;
#pragma unroll
            for (int cc = 0; cc < 2; cc++)
                *(short8*)(base + (mtk * 2 + cc) * 512 + h * 256 + l31 * 8) =
                    cfrag_chunk(pkc, cc, h);
        }
    }
}

// ---------------------------------------------------------------------------
// flash7: flash6 loop verbatim + (a) XCD-aware block swizzle so all 32 blocks
// of one bh share one XCD's L2 (blk%8 heuristic); (b) epilogue converts the
// O C-frags to operand-frag layout (cfrag_chunk) and stores b128 tiles:
//   Opart[ksp][bh][qt][kc4][h][l31][8] (bf16) — back1's B operand, directly.
// ---------------------------------------------------------------------------
__global__ __launch_bounds__(256) void flash7(const ushort* __restrict__ qtile,
                                              const ushort* __restrict__ ktile,
                                              const ushort* __restrict__ vtile,
                                              ushort* __restrict__ Opart,
                                              float* __restrict__ lbuf) {
    const int wave = threadIdx.x >> 6, lane = threadIdx.x & 63;
    const int l31 = lane & 31, h = lane >> 5;
    const int blk = blockIdx.x;
    const int xcd = blk & 7, j = blk >> 3;        // j 0..127
    const int bh = xcd * 4 + (j & 3);             // all 32 blocks of bh on 1 XCD
    const int inner = j >> 2;                     // 0..31
    const int ksp = inner >> 4;
    const int qt = (inner & 15) * 4 + wave;       // 4 waves share the K/V stream
    const int fo = h * 256 + l31 * 8;

    const ushort* qtb = qtile + ((size_t)bh * 64 + qt) * 2048;
    short8 qf[4];
#pragma unroll
    for (int kc = 0; kc < 4; kc++) qf[kc] = *(const short8*)(qtb + kc * 512 + fo);

    const ushort* ktb = ktile + (size_t)bh * 32 * 4096;
    const ushort* vtb = vtile + (size_t)bh * 32 * 4096;

    S8U ones;
    ones.u[0] = make_uint2(0x3F803F80u, 0x3F803F80u);
    ones.u[1] = make_uint2(0x3F803F80u, 0x3F803F80u);

    float16v O0 = {}, O1 = {}, La = {};

    for (int kblk = ksp * 16; kblk < ksp * 16 + 16; kblk++) {
        const ushort* kb_ = ktb + (size_t)kblk * 4096;
        const ushort* vb_ = vtb + (size_t)kblk * 4096;
        short8 kf[2][4];
#pragma unroll
        for (int mt = 0; mt < 2; mt++)
#pragma unroll
            for (int kc = 0; kc < 4; kc++)
                kf[mt][kc] = *(const short8*)(kb_ + mt * 2048 + kc * 512 + fo);
        float16v s0 = {}, s1 = {};
#pragma unroll
        for (int kc = 0; kc < 4; kc++) {
            s0 = __builtin_amdgcn_mfma_f32_32x32x16_bf16(kf[0][kc], qf[kc], s0, 0, 0, 0);
            s1 = __builtin_amdgcn_mfma_f32_32x32x16_bf16(kf[1][kc], qf[kc], s1, 0, 0, 0);
        }
        short8 vf[2][4];
#pragma unroll
        for (int mt = 0; mt < 2; mt++)
#pragma unroll
            for (int kc = 0; kc < 4; kc++)
                vf[mt][kc] = *(const short8*)(vb_ + mt * 2048 + kc * 512 + fo);

        unsigned pk0[8], pk1[8];
#pragma unroll
        for (int j2 = 0; j2 < 8; j2++) {
            pk0[j2] = pk2(__builtin_amdgcn_exp2f(s0[2 * j2]),
                          __builtin_amdgcn_exp2f(s0[2 * j2 + 1]));
            pk1[j2] = pk2(__builtin_amdgcn_exp2f(s1[2 * j2]),
                          __builtin_amdgcn_exp2f(s1[2 * j2 + 1]));
        }
#pragma unroll
        for (int kc = 0; kc < 4; kc++) {
            const unsigned* pkm = (kc < 2) ? pk0 : pk1;
            short8 bf = cfrag_chunk(pkm, kc & 1, h);
            La = __builtin_amdgcn_mfma_f32_32x32x16_bf16(ones.v, bf, La, 0, 0, 0);
            O0 = __builtin_amdgcn_mfma_f32_32x32x16_bf16(vf[0][kc], bf, O0, 0, 0, 0);
            O1 = __builtin_amdgcn_mfma_f32_32x32x16_bf16(vf[1][kc], bf, O1, 0, 0, 0);
        }
    }

    // ---- epilogue: C-frag -> operand-frag tiles, b128 stores ----
    if (h == 0) lbuf[(size_t)ksp * 65536 + bh * 2048 + qt * 32 + l31] = La[0];
    ushort* ob = Opart + (size_t)ksp * 4194304 + ((size_t)bh * 64 + qt) * 2048;
#pragma unroll
    for (int mt = 0; mt < 2; mt++) {
        float16v Ov = mt ? O1 : O0;
        unsigned pkO[8];
#pragma unroll
        for (int j2 = 0; j2 < 8; j2++) pkO[j2] = pk2(Ov[2 * j2], Ov[2 * j2 + 1]);
#pragma unroll
        for (int cc = 0; cc < 2; cc++)
            *(short8*)(ob + ((mt * 2 + cc) * 2 + h) * 256 + l31 * 8) =
                cfrag_chunk(pkO, cc, h);
    }
}

// ---------------------------------------------------------------------------
// back1: grid 512 = rg(128) x hq(4); wave = 1 head.  B operand = Opart frag
// tiles (b128 loads), unpack + ksp-sum + per-lane(q) normalize + repack.
//   respart2[hq][rg][r][lane] fp32, 2 MB.
// ---------------------------------------------------------------------------
__global__ __launch_bounds__(256) void back1_kern(const ushort* __restrict__ Opart,
                                                  const float* __restrict__ lbuf,
                                                  const ushort* __restrict__ bF,
                                                  float* __restrict__ respart2) {
    __shared__ float red[4 * 16 * 64];       // 16 KB
    const int t = threadIdx.x, wave = t >> 6, lane = t & 63;
    const int l31 = lane & 31, h = lane >> 5;
    const int hq = blockIdx.x & 3, rg = blockIdx.x >> 2;
    const int b = rg >> 6, qt = rg & 63;
    const int hd = hq * 4 + wave, bh = b * NH + hd;

    float lb = lbuf[(size_t)bh * 2048 + qt * 32 + l31] +
               lbuf[(size_t)65536 + (size_t)bh * 2048 + qt * 32 + l31];
    float invl = 1.0f / lb;
    const ushort* ob0 = Opart + ((size_t)bh * 64 + qt) * 2048;
    const ushort* ob1 = ob0 + 4194304;

    float16v c = {};
#pragma unroll
    for (int kc = 0; kc < 4; kc++) {
        short8 o0 = *(const short8*)(ob0 + (kc * 2 + h) * 256 + l31 * 8);
        short8 o1 = *(const short8*)(ob1 + (kc * 2 + h) * 256 + l31 * 8);
        float av[8];
#pragma unroll
        for (int e = 0; e < 8; e++)
            av[e] = (ubf((ushort)o0[e]) + ubf((ushort)o1[e])) * invl;
        S8U bn;
        bn.u[0] = make_uint2(pk2(av[0], av[1]), pk2(av[2], av[3]));
        bn.u[1] = make_uint2(pk2(av[4], av[5]), pk2(av[6], av[7]));
        int kcg = hd * 4 + kc;                // global channel chunk 0..63
        short8 a = *(const short8*)(bF + ((size_t)((3 * 64 + kcg) * 2 + h) * 32 + l31) * 8);
        c = __builtin_amdgcn_mfma_f32_32x32x16_bf16(a, bn.v, c, 0, 0, 0);
    }
#pragma unroll
    for (int r = 0; r < 16; r++) red[wave * 1024 + r * 64 + lane] = c[r];
    __syncthreads();
#pragma unroll
    for (int i = 0; i < 4; i++) {
        int e = i * 256 + t;
        respart2[((size_t)hq * 128 + rg) * 1024 + e] =
            (red[e] + red[1024 + e]) + (red[2048 + e] + red[3072 + e]);
    }
}

// ---------------------------------------------------------------------------
// back2: unchanged (verified round 8).
// ---------------------------------------------------------------------------
__global__ __launch_bounds__(256) void back2_kern(const float* __restrict__ respart2,
                                                  const ushort* __restrict__ wobF,
                                                  float* __restrict__ out) {
    const int t = threadIdx.x, wave = t >> 6, lane = t & 63;
    const int l31 = lane & 31, h = lane >> 5;
    const int ng = blockIdx.x & 7, rg = blockIdx.x >> 3;

    float cf[16];
#pragma unroll
    for (int r = 0; r < 16; r++) {
        const float* pp = respart2 + r * 64 + lane;
        cf[r] = (pp[(size_t)rg * 1024] + pp[(size_t)(128 + rg) * 1024]) +
                (pp[(size_t)(256 + rg) * 1024] + pp[(size_t)(384 + rg) * 1024]);
    }
    unsigned pkr[8];
#pragma unroll
    for (int j = 0; j < 8; j++) pkr[j] = pk2(cf[2 * j], cf[2 * j + 1]);
    short8 a0 = cfrag_chunk(pkr, 0, h);
    short8 a1 = cfrag_chunk(pkr, 1, h);

    int nt = ng * 4 + wave;
    const ushort* wp = wobF + (size_t)nt * 1024;   // [kc2][h][l31][8]
    short8 wf0 = *(const short8*)(wp + (size_t)h * 256 + l31 * 8);
    short8 wf1 = *(const short8*)(wp + (size_t)(2 + h) * 256 + l31 * 8);
    float16v co = {};
    co = __builtin_amdgcn_mfma_f32_32x32x16_bf16(a0, wf0, co, 0, 0, 0);
    co = __builtin_amdgcn_mfma_f32_32x32x16_bf16(a1, wf1, co, 0, 0, 0);
#pragma unroll
    for (int r = 0; r < 16; r++) {
        int row = rg * 32 + crow(r, h);
        out[(size_t)row * CD + nt * 32 + l31] = co[r];
    }
}

// ---------------------------------------------------------------------------
extern "C" void kernel_launch(void* const* d_in, const int* in_sizes, int n_in,
                              void* d_out, int out_size, void* d_ws, size_t ws_size,
                              hipStream_t stream) {
    const float* x  = (const float*)d_in[0];
    const float* bq = (const float*)d_in[1];
    const float* pq = (const float*)d_in[2];
    const float* aq = (const float*)d_in[3];
    const float* bk = (const float*)d_in[4];
    const float* pk = (const float*)d_in[5];
    const float* ak = (const float*)d_in[6];
    const float* bv = (const float*)d_in[7];
    const float* pv = (const float*)d_in[8];
    const float* av = (const float*)d_in[9];
    const float* bo = (const float*)d_in[10];
    const float* po = (const float*)d_in[11];
    const float* ao = (const float*)d_in[12];

    char* ws = (char*)d_ws;
    ushort* bF    = (ushort*)(ws + 0);          // 256 KB
    ushort* wqkvF = (ushort*)(ws + 262144);     // 192 KB
    ushort* wobF  = (ushort*)(ws + 458752);     //  64 KB
    ushort* qtile = (ushort*)(ws + 524288);     //   8 MB
    ushort* ktile = (ushort*)(ws + 8912896);    //   8 MB
    ushort* vtile = (ushort*)(ws + 17301504);   //   8 MB
    ushort* Opart = (ushort*)(ws + 25690112);   //  16 MB (2 ksp x 8 MB, bf16)
    float*  lbuf  = (float*)(ws + 42467328);    // 512 KB (2 ksp) -> ~43 MB total
    // aliases (lifetimes disjoint in stream order):
    float* respart  = (float*)(ws + 25690112);  // 6 MB, dead before flash7 writes Opart
    float* respart2 = (float*)(ws + 524288);    // 2 MB, qtile dead after flash7

    prep_kern<<<128, 256, 0, stream>>>(bq, bk, bv, bo, pq, aq, pk, ak, pv, av,
                                       po, ao, bF, wqkvF, wobF);
    res_part_kern<<<512, 256, 0, stream>>>(x, bF, respart);
    qkv_kern<<<512, 256, 0, stream>>>(respart, wqkvF, qtile, ktile, vtile);
    flash7<<<BSZ * NH * 32, 256, 0, stream>>>(qtile, ktile, vtile, Opart, lbuf);
    back1_kern<<<512, 256, 0, stream>>>(Opart, lbuf, bF, respart2);
    back2_kern<<<1024, 256, 0, stream>>>(respart2, wobF, (float*)d_out);
}

// Round 10
// 204.092 us; speedup vs baseline: 1.4963x; 1.4963x over previous
//
#include <hip/hip_runtime.h>
#include <hip/hip_bf16.h>
#include <cstdint>
#include <cstddef>

#define NH   16
#define HD   64
#define CD   1024
#define HARM 32
#define BSZ  2
#define LSEQ 2048
#define NROW (BSZ*LSEQ)   // 4096

typedef __attribute__((ext_vector_type(8))) short short8;     // 8 bf16 (A/B frag)
typedef __attribute__((ext_vector_type(16))) float float16v;  // 32x32 C frag

__device__ inline ushort bf16u(float f) {
    __hip_bfloat16 h = __float2bfloat16(f);
    return *(ushort*)&h;
}
__device__ inline float ubf(ushort u) {
    return __uint_as_float((unsigned)u << 16);
}
__device__ inline unsigned pk2(float a, float b) {
    return (unsigned)bf16u(a) | ((unsigned)bf16u(b) << 16);
}
// C-frag register r -> row offset within 32-row tile
__device__ inline int crow(int r, int half) { return (r & 3) + 8 * (r >> 2) + 4 * half; }

union S8U { short8 v; uint2 u[2]; };

// Half-swap transform (verified flash3..8): C-frag regs (8 packed uints,
// pk[j] = m-values {8*(j>>1)+4h+2*(j&1), +1}) -> one A/B-frag 16-k chunk cc.
// Result frag: lane = former C column, k = former C rows.
__device__ inline short8 cfrag_chunk(const unsigned* pk, int cc, int h) {
    int gb2 = cc * 4;
    unsigned B0, B1, B2, B3;
    {
        unsigned v0 = pk[gb2], v1 = pk[gb2 + 2];
        unsigned send = h ? v0 : v1;
        unsigned rem = (unsigned)__shfl_xor((int)send, 32, 64);
        B0 = h ? rem : v0;
        B2 = h ? v1 : rem;
    }
    {
        unsigned v0 = pk[gb2 + 1], v1 = pk[gb2 + 3];
        unsigned send = h ? v0 : v1;
        unsigned rem = (unsigned)__shfl_xor((int)send, 32, 64);
        B1 = h ? rem : v0;
        B3 = h ? v1 : rem;
    }
    S8U bf;
    bf.u[0] = make_uint2(B0, B1);
    bf.u[1] = make_uint2(B2, B3);
    return bf.v;
}

// ---------------------------------------------------------------------------
// prep: fragment-tile all weights (unchanged, verified).
// ---------------------------------------------------------------------------
__global__ void prep_kern(const float* __restrict__ bq, const float* __restrict__ bk,
                          const float* __restrict__ bv, const float* __restrict__ bo,
                          const float* __restrict__ pq, const float* __restrict__ aq,
                          const float* __restrict__ pk, const float* __restrict__ ak,
                          const float* __restrict__ pv, const float* __restrict__ av,
                          const float* __restrict__ po, const float* __restrict__ ao,
                          ushort* __restrict__ bF, ushort* __restrict__ wqkvF,
                          ushort* __restrict__ wobF) {
    const float QSCALE = 0.125f * 1.44269504088896340736f;  // hd^-0.5 * log2e
    unsigned tid = blockIdx.x * 256 + threadIdx.x;
    if (tid < 16384) {                 // bF
        unsigned l31 = tid & 31, h = (tid >> 5) & 1, kc = (tid >> 6) & 63, proj = tid >> 12;
        const float* bp = (proj == 0) ? bq : (proj == 1) ? bk : (proj == 2) ? bv : bo;
        const float* s = bp + (size_t)l31 * CD + kc * 16 + h * 8;
        float4 f0 = *(const float4*)s, f1 = *(const float4*)(s + 4);
        S8U o;
        o.u[0] = make_uint2(pk2(f0.x, f0.y), pk2(f0.z, f0.w));
        o.u[1] = make_uint2(pk2(f1.x, f1.y), pk2(f1.z, f1.w));
        *(short8*)(bF + (size_t)tid * 8) = o.v;
        return;
    }
    if (tid < 28672) {                 // wqkvF
        unsigned i = tid - 16384;
        unsigned l31 = i & 31, h = (i >> 5) & 1, kc2 = (i >> 6) & 1;
        unsigned ntp = (i >> 7) & 31, proj = i >> 12;
        const float* ph = (proj == 0) ? pq : (proj == 1) ? pk : pv;
        const float* am = (proj == 0) ? aq : (proj == 1) ? ak : av;
        float sc = (proj == 0) ? QSCALE : 1.0f;
        size_t s = (size_t)(ntp * 32 + l31) * HARM + kc2 * 16 + h * 8;
        float4 p0 = *(const float4*)(ph + s), p1 = *(const float4*)(ph + s + 4);
        float4 a0 = *(const float4*)(am + s), a1 = *(const float4*)(am + s + 4);
        S8U o;
        o.u[0] = make_uint2(pk2(a0.x * cosf(p0.x) * sc, a0.y * cosf(p0.y) * sc),
                            pk2(a0.z * cosf(p0.z) * sc, a0.w * cosf(p0.w) * sc));
        o.u[1] = make_uint2(pk2(a1.x * cosf(p1.x) * sc, a1.y * cosf(p1.y) * sc),
                            pk2(a1.z * cosf(p1.z) * sc, a1.w * cosf(p1.w) * sc));
        *(short8*)(wqkvF + (size_t)i * 8) = o.v;
        return;
    }
    {                                  // wobF
        unsigned i = tid - 28672;      // 4096
        unsigned l31 = i & 31, h = (i >> 5) & 1, kc2 = (i >> 6) & 1, nt = i >> 7;
        size_t s = (size_t)(nt * 32 + l31) * HARM + kc2 * 16 + h * 8;
        float4 p0 = *(const float4*)(po + s), p1 = *(const float4*)(po + s + 4);
        float4 a0 = *(const float4*)(ao + s), a1 = *(const float4*)(ao + s + 4);
        S8U o;
        o.u[0] = make_uint2(pk2(a0.x * cosf(p0.x), a0.y * cosf(p0.y)),
                            pk2(a0.z * cosf(p0.z), a0.w * cosf(p0.w)));
        o.u[1] = make_uint2(pk2(a1.x * cosf(p1.x), a1.y * cosf(p1.y)),
                            pk2(a1.z * cosf(p1.z), a1.w * cosf(p1.w)));
        *(short8*)(wobF + (size_t)i * 8) = o.v;
    }
}

// ---------------------------------------------------------------------------
// res_part: unchanged (verified round 8).  respart now a dedicated region.
//   respart[kseg][rg][p][r][lane]  fp32, 6 MB total
// ---------------------------------------------------------------------------
__global__ __launch_bounds__(256) void res_part_kern(const float* __restrict__ x,
                                                     const ushort* __restrict__ bF,
                                                     float* __restrict__ respart) {
    __shared__ ushort xs[32 * 256];          // 16 KB
    __shared__ float red[4 * 16 * 64];       // 16 KB
    const int t = threadIdx.x, wave = t >> 6, lane = t & 63;
    const int l31 = lane & 31, h = lane >> 5;
    const int kseg = blockIdx.x & 3, rg = blockIdx.x >> 2;
    const int n0 = rg * 32;

#pragma unroll
    for (int i = 0; i < 8; i++) {
        int idx = i * 256 + t, row = idx >> 6, c4 = idx & 63;
        float4 v = *(const float4*)(x + (size_t)(n0 + row) * CD + kseg * 256 + c4 * 4);
        int chunk = (c4 >> 1) ^ (row & 15), sub = c4 & 1;
        *(ushort4*)(&xs[row * 256 + chunk * 8 + sub * 4]) =
            make_ushort4(bf16u(v.x), bf16u(v.y), bf16u(v.z), bf16u(v.w));
    }
    __syncthreads();

    float16v resC[3] = {};
#pragma unroll
    for (int kci = 0; kci < 4; kci++) {
        int c = wave * 8 + kci * 2 + h;
        short8 bx = *(const short8*)(&xs[l31 * 256 + (c ^ (l31 & 15)) * 8]);
        int kcg = kseg * 16 + wave * 4 + kci;
#pragma unroll
        for (int p = 0; p < 3; p++) {
            short8 a = *(const short8*)(bF + ((size_t)((p * 64 + kcg) * 2 + h) * 32 + l31) * 8);
            resC[p] = __builtin_amdgcn_mfma_f32_32x32x16_bf16(a, bx, resC[p], 0, 0, 0);
        }
    }
    float* outb = respart + ((size_t)(kseg * 128 + rg) * 3) * 1024;
    for (int p = 0; p < 3; p++) {
        __syncthreads();
#pragma unroll
        for (int r = 0; r < 16; r++) red[wave * 1024 + r * 64 + lane] = resC[p][r];
        __syncthreads();
#pragma unroll
        for (int i = 0; i < 4; i++) {
            int e = i * 256 + t;
            outb[p * 1024 + e] = (red[e] + red[1024 + e]) + (red[2048 + e] + red[3072 + e]);
        }
    }
}

// ---------------------------------------------------------------------------
// qkv: round-8 math, 1024 blocks (8 segs x 4 waves x 3 tiles) for 2x TLP.
// ---------------------------------------------------------------------------
__global__ __launch_bounds__(256) void qkv_kern(const float* __restrict__ respart,
                                                const ushort* __restrict__ wqkvF,
                                                ushort* __restrict__ qtile,
                                                ushort* __restrict__ ktile,
                                                ushort* __restrict__ vtile) {
    const int t = threadIdx.x, wave = t >> 6, lane = t & 63;
    const int l31 = lane & 31, h = lane >> 5;
    const int seg = blockIdx.x & 7, rest = blockIdx.x >> 3;
    const int b = rest >> 6, l0q = rest & 63;

    short8 rf[3][2];
#pragma unroll
    for (int p = 0; p < 3; p++) {
        float cf[16];
#pragma unroll
        for (int r = 0; r < 16; r++) {
            const float* pp = respart + (size_t)p * 1024 + r * 64 + lane;
            cf[r] = (pp[(size_t)rest * 3072] +
                     pp[(size_t)(128 + rest) * 3072]) +
                    (pp[(size_t)(256 + rest) * 3072] +
                     pp[(size_t)(384 + rest) * 3072]);
        }
        unsigned pkr[8];
#pragma unroll
        for (int j = 0; j < 8; j++) pkr[j] = pk2(cf[2 * j], cf[2 * j + 1]);
        rf[p][0] = cfrag_chunk(pkr, 0, h);
        rf[p][1] = cfrag_chunk(pkr, 1, h);
    }

    const int kblk = l0q >> 1, mtk = l0q & 1;
    for (int i = 0; i < 3; i++) {
        int nt = (seg * 4 + wave) * 3 + i;
        int proj = nt >> 5, ntp = nt & 31;
        int head = ntp >> 1, sub = ntp & 1;
        const ushort* wp = wqkvF + ((size_t)(proj * 32 + ntp) * 4) * 256;  // [kc2][h][l31][8]
        short8 wf0 = *(const short8*)(wp + (size_t)h * 256 + l31 * 8);
        short8 wf1 = *(const short8*)(wp + (size_t)(2 + h) * 256 + l31 * 8);
        float16v c = {};
        if (proj < 2) {   // A=w (lane=ch), B=res (lane=row) -> C col=row
            c = __builtin_amdgcn_mfma_f32_32x32x16_bf16(wf0, rf[proj][0], c, 0, 0, 0);
            c = __builtin_amdgcn_mfma_f32_32x32x16_bf16(wf1, rf[proj][1], c, 0, 0, 0);
        } else {          // A=res (lane=row), B=w (lane=ch) -> C col=ch
            c = __builtin_amdgcn_mfma_f32_32x32x16_bf16(rf[2][0], wf0, c, 0, 0, 0);
            c = __builtin_amdgcn_mfma_f32_32x32x16_bf16(rf[2][1], wf1, c, 0, 0, 0);
        }
        unsigned pkc[8];
#pragma unroll
        for (int j = 0; j < 8; j++) pkc[j] = pk2(c[2 * j], c[2 * j + 1]);

        if (proj == 0) {
            ushort* base = qtile + (((size_t)(b * NH + head) * 64 + l0q)) * 2048;
#pragma unroll
            for (int cc = 0; cc < 2; cc++)
                *(short8*)(base + (sub * 2 + cc) * 512 + h * 256 + l31 * 8) =
                    cfrag_chunk(pkc, cc, h);
        } else if (proj == 1) {
            ushort* base = ktile + ((size_t)(b * NH + head) * 32 + kblk) * 4096 + mtk * 2048;
#pragma unroll
            for (int cc = 0; cc < 2; cc++)
                *(short8*)(base + (sub * 2 + cc) * 512 + h * 256 + l31 * 8) =
                    cfrag_chunk(pkc, cc, h);
        } else {
            ushort* base = vtile + ((size_t)(b * NH + head) * 32 + kblk) * 4096 + sub * 2048;
#pragma unroll
            for (int cc = 0; cc < 2; cc++)
                *(short8*)(base + (mtk * 2 + cc) * 512 + h * 256 + l31 * 8) =
                    cfrag_chunk(pkc, cc, h);
        }
    }
}

// ---------------------------------------------------------------------------
// flash8: round-8 block mapping (measured 64.6 us; XCD swizzle REVERTED) +
// round-9 operand-frag epilogue (4 b128 stores):
//   Opart[ksp][bh][qt][kc4][h][l31][8] (bf16), lbuf[ksp][bh][2048] (fp32)
// ---------------------------------------------------------------------------
__global__ __launch_bounds__(256) void flash8(const ushort* __restrict__ qtile,
                                              const ushort* __restrict__ ktile,
                                              const ushort* __restrict__ vtile,
                                              ushort* __restrict__ Opart,
                                              float* __restrict__ lbuf) {
    const int wave = threadIdx.x >> 6, lane = threadIdx.x & 63;
    const int l31 = lane & 31, h = lane >> 5;
    const int bh = blockIdx.x >> 5;
    const int inner = blockIdx.x & 31;
    const int ksp = inner >> 4;
    const int qt = (inner & 15) * 4 + wave;       // 4 waves share the K/V stream
    const int fo = h * 256 + l31 * 8;

    const ushort* qtb = qtile + ((size_t)bh * 64 + qt) * 2048;
    short8 qf[4];
#pragma unroll
    for (int kc = 0; kc < 4; kc++) qf[kc] = *(const short8*)(qtb + kc * 512 + fo);

    const ushort* ktb = ktile + (size_t)bh * 32 * 4096;
    const ushort* vtb = vtile + (size_t)bh * 32 * 4096;

    S8U ones;
    ones.u[0] = make_uint2(0x3F803F80u, 0x3F803F80u);
    ones.u[1] = make_uint2(0x3F803F80u, 0x3F803F80u);

    float16v O0 = {}, O1 = {}, La = {};

    for (int kblk = ksp * 16; kblk < ksp * 16 + 16; kblk++) {
        const ushort* kb_ = ktb + (size_t)kblk * 4096;
        const ushort* vb_ = vtb + (size_t)kblk * 4096;
        short8 kf[2][4];
#pragma unroll
        for (int mt = 0; mt < 2; mt++)
#pragma unroll
            for (int kc = 0; kc < 4; kc++)
                kf[mt][kc] = *(const short8*)(kb_ + mt * 2048 + kc * 512 + fo);
        float16v s0 = {}, s1 = {};
#pragma unroll
        for (int kc = 0; kc < 4; kc++) {
            s0 = __builtin_amdgcn_mfma_f32_32x32x16_bf16(kf[0][kc], qf[kc], s0, 0, 0, 0);
            s1 = __builtin_amdgcn_mfma_f32_32x32x16_bf16(kf[1][kc], qf[kc], s1, 0, 0, 0);
        }
        short8 vf[2][4];
#pragma unroll
        for (int mt = 0; mt < 2; mt++)
#pragma unroll
            for (int kc = 0; kc < 4; kc++)
                vf[mt][kc] = *(const short8*)(vb_ + mt * 2048 + kc * 512 + fo);

        unsigned pk0[8], pk1[8];
#pragma unroll
        for (int j2 = 0; j2 < 8; j2++) {
            pk0[j2] = pk2(__builtin_amdgcn_exp2f(s0[2 * j2]),
                          __builtin_amdgcn_exp2f(s0[2 * j2 + 1]));
            pk1[j2] = pk2(__builtin_amdgcn_exp2f(s1[2 * j2]),
                          __builtin_amdgcn_exp2f(s1[2 * j2 + 1]));
        }
#pragma unroll
        for (int kc = 0; kc < 4; kc++) {
            const unsigned* pkm = (kc < 2) ? pk0 : pk1;
            short8 bf = cfrag_chunk(pkm, kc & 1, h);
            La = __builtin_amdgcn_mfma_f32_32x32x16_bf16(ones.v, bf, La, 0, 0, 0);
            O0 = __builtin_amdgcn_mfma_f32_32x32x16_bf16(vf[0][kc], bf, O0, 0, 0, 0);
            O1 = __builtin_amdgcn_mfma_f32_32x32x16_bf16(vf[1][kc], bf, O1, 0, 0, 0);
        }
    }

    // ---- epilogue: C-frag -> operand-frag tiles, b128 stores ----
    if (h == 0) lbuf[(size_t)ksp * 65536 + bh * 2048 + qt * 32 + l31] = La[0];
    ushort* ob = Opart + (size_t)ksp * 4194304 + ((size_t)bh * 64 + qt) * 2048;
#pragma unroll
    for (int mt = 0; mt < 2; mt++) {
        float16v Ov = mt ? O1 : O0;
        unsigned pkO[8];
#pragma unroll
        for (int j2 = 0; j2 < 8; j2++) pkO[j2] = pk2(Ov[2 * j2], Ov[2 * j2 + 1]);
#pragma unroll
        for (int cc = 0; cc < 2; cc++)
            *(short8*)(ob + ((mt * 2 + cc) * 2 + h) * 256 + l31 * 8) =
                cfrag_chunk(pkO, cc, h);
    }
}

// ---------------------------------------------------------------------------
// back1: unchanged from round 9 (b128 frag loads).
//   respart2[hq][rg][r][lane] fp32, 2 MB (aliases qtile; provably safe).
// ---------------------------------------------------------------------------
__global__ __launch_bounds__(256) void back1_kern(const ushort* __restrict__ Opart,
                                                  const float* __restrict__ lbuf,
                                                  const ushort* __restrict__ bF,
                                                  float* __restrict__ respart2) {
    __shared__ float red[4 * 16 * 64];       // 16 KB
    const int t = threadIdx.x, wave = t >> 6, lane = t & 63;
    const int l31 = lane & 31, h = lane >> 5;
    const int hq = blockIdx.x & 3, rg = blockIdx.x >> 2;
    const int b = rg >> 6, qt = rg & 63;
    const int hd = hq * 4 + wave, bh = b * NH + hd;

    float lb = lbuf[(size_t)bh * 2048 + qt * 32 + l31] +
               lbuf[(size_t)65536 + (size_t)bh * 2048 + qt * 32 + l31];
    float invl = 1.0f / lb;
    const ushort* ob0 = Opart + ((size_t)bh * 64 + qt) * 2048;
    const ushort* ob1 = ob0 + 4194304;

    float16v c = {};
#pragma unroll
    for (int kc = 0; kc < 4; kc++) {
        short8 o0 = *(const short8*)(ob0 + (kc * 2 + h) * 256 + l31 * 8);
        short8 o1 = *(const short8*)(ob1 + (kc * 2 + h) * 256 + l31 * 8);
        float av[8];
#pragma unroll
        for (int e = 0; e < 8; e++)
            av[e] = (ubf((ushort)o0[e]) + ubf((ushort)o1[e])) * invl;
        S8U bn;
        bn.u[0] = make_uint2(pk2(av[0], av[1]), pk2(av[2], av[3]));
        bn.u[1] = make_uint2(pk2(av[4], av[5]), pk2(av[6], av[7]));
        int kcg = hd * 4 + kc;                // global channel chunk 0..63
        short8 a = *(const short8*)(bF + ((size_t)((3 * 64 + kcg) * 2 + h) * 32 + l31) * 8);
        c = __builtin_amdgcn_mfma_f32_32x32x16_bf16(a, bn.v, c, 0, 0, 0);
    }
#pragma unroll
    for (int r = 0; r < 16; r++) red[wave * 1024 + r * 64 + lane] = c[r];
    __syncthreads();
#pragma unroll
    for (int i = 0; i < 4; i++) {
        int e = i * 256 + t;
        respart2[((size_t)hq * 128 + rg) * 1024 + e] =
            (red[e] + red[1024 + e]) + (red[2048 + e] + red[3072 + e]);
    }
}

// ---------------------------------------------------------------------------
// back2: unchanged (verified round 8).
// ---------------------------------------------------------------------------
__global__ __launch_bounds__(256) void back2_kern(const float* __restrict__ respart2,
                                                  const ushort* __restrict__ wobF,
                                                  float* __restrict__ out) {
    const int t = threadIdx.x, wave = t >> 6, lane = t & 63;
    const int l31 = lane & 31, h = lane >> 5;
    const int ng = blockIdx.x & 7, rg = blockIdx.x >> 3;

    float cf[16];
#pragma unroll
    for (int r = 0; r < 16; r++) {
        const float* pp = respart2 + r * 64 + lane;
        cf[r] = (pp[(size_t)rg * 1024] + pp[(size_t)(128 + rg) * 1024]) +
                (pp[(size_t)(256 + rg) * 1024] + pp[(size_t)(384 + rg) * 1024]);
    }
    unsigned pkr[8];
#pragma unroll
    for (int j = 0; j < 8; j++) pkr[j] = pk2(cf[2 * j], cf[2 * j + 1]);
    short8 a0 = cfrag_chunk(pkr, 0, h);
    short8 a1 = cfrag_chunk(pkr, 1, h);

    int nt = ng * 4 + wave;
    const ushort* wp = wobF + (size_t)nt * 1024;   // [kc2][h][l31][8]
    short8 wf0 = *(const short8*)(wp + (size_t)h * 256 + l31 * 8);
    short8 wf1 = *(const short8*)(wp + (size_t)(2 + h) * 256 + l31 * 8);
    float16v co = {};
    co = __builtin_amdgcn_mfma_f32_32x32x16_bf16(a0, wf0, co, 0, 0, 0);
    co = __builtin_amdgcn_mfma_f32_32x32x16_bf16(a1, wf1, co, 0, 0, 0);
#pragma unroll
    for (int r = 0; r < 16; r++) {
        int row = rg * 32 + crow(r, h);
        out[(size_t)row * CD + nt * 32 + l31] = co[r];
    }
}

// ---------------------------------------------------------------------------
extern "C" void kernel_launch(void* const* d_in, const int* in_sizes, int n_in,
                              void* d_out, int out_size, void* d_ws, size_t ws_size,
                              hipStream_t stream) {
    const float* x  = (const float*)d_in[0];
    const float* bq = (const float*)d_in[1];
    const float* pq = (const float*)d_in[2];
    const float* aq = (const float*)d_in[3];
    const float* bk = (const float*)d_in[4];
    const float* pk = (const float*)d_in[5];
    const float* ak = (const float*)d_in[6];
    const float* bv = (const float*)d_in[7];
    const float* pv = (const float*)d_in[8];
    const float* av = (const float*)d_in[9];
    const float* bo = (const float*)d_in[10];
    const float* po = (const float*)d_in[11];
    const float* ao = (const float*)d_in[12];

    char* ws = (char*)d_ws;
    ushort* bF      = (ushort*)(ws + 0);          // 256 KB
    ushort* wqkvF   = (ushort*)(ws + 262144);     // 192 KB
    ushort* wobF    = (ushort*)(ws + 458752);     //  64 KB
    ushort* qtile   = (ushort*)(ws + 524288);     //   8 MB
    ushort* ktile   = (ushort*)(ws + 8912896);    //   8 MB
    ushort* vtile   = (ushort*)(ws + 17301504);   //   8 MB
    ushort* Opart   = (ushort*)(ws + 25690112);   //  16 MB (2 ksp x 8 MB, bf16)
    float*  lbuf    = (float*)(ws + 42467328);    // 512 KB
    float*  respart = (float*)(ws + 42991616);    //   6 MB dedicated -> ~49 MB total
    float*  respart2= (float*)(ws + 524288);      //   2 MB alias of qtile (safe:
                                                  //   qtile fully rewritten each iter)

    prep_kern<<<128, 256, 0, stream>>>(bq, bk, bv, bo, pq, aq, pk, ak, pv, av,
                                       po, ao, bF, wqkvF, wobF);
    res_part_kern<<<512, 256, 0, stream>>>(x, bF, respart);
    qkv_kern<<<1024, 256, 0, stream>>>(respart, wqkvF, qtile, ktile, vtile);
    flash8<<<BSZ * NH * 32, 256, 0, stream>>>(qtile, ktile, vtile, Opart, lbuf);
    back1_kern<<<512, 256, 0, stream>>>(Opart, lbuf, bF, respart2);
    back2_kern<<<1024, 256, 0, stream>>>(respart2, wobF, (float*)d_out);
}